// Round 1
// baseline (646.934 us; speedup 1.0000x reference)
//
#include <hip/hip_runtime.h>

// ============================================================================
// Talking-heads attention, MI355X bf16-MFMA implementation (v1, correctness-first)
//
// Pipeline (all on `stream`):
//  1. ln_kernel      : x(f32) -> xn(bf16)                        [4096,1024]
//  2. wcvt_t x3      : W(f32)[K][N] -> WT(bf16)[N][K]            (Wq,Wkv,Wout)
//  3. gemm_bt        : q  = xn @ Wq * 0.125  (scale folded)      [4096,1024] bf16
//  4. gemm_bt        : kv = xn @ Wkv                             [4096,2048] bf16
//  5. v_transpose    : VT[b][g][d][n] <- kv[:, 1024+g*64+d]      bf16
//  6. attn<0>        : pass A: l[g,i] = sum_j exp(S2-8)          (fixed-shift softmax)
//  7. attn<1>        : pass B: P=exp(S2-8)/l -> mix_post -> PV -> oattn bf16
//  8. gemm_bt<f32,bias>: d_out = oattn @ Wout + bout             f32
//
// attn kernel: WG = (b, 16 query rows), 16 waves (wave = head for QK / = g' for PV).
//  Per 32-wide K-tile: QK^T swapped (A=K,B=Q) -> S^T written b64 to LDS blocked
//  [chunk=2*i+jc][h][c_lo]; mix_pre/mix_post as MFMA with pre-halved mix matrix
//  (duplicated k-halves; A/B share positional k-rule so HW k-map is irrelevant);
//  PV uses P3 LDS [g'][i][j] + VT global B-frags (shared rule k=8q+e).
//  2 barriers/step (P2 chunk is wave-local; other hazards covered — see analysis).
// ============================================================================

#define NSEQ 2048
#define DIM  1024
#define NH   16
#define DH   64
#define MHAT 8.0f
#define L2E  1.4426950408889634f

typedef unsigned short u16;
typedef unsigned int   u32;
typedef __attribute__((ext_vector_type(4))) float  f32x4;
typedef __attribute__((ext_vector_type(8))) __bf16 bf16x8;
typedef __attribute__((ext_vector_type(4))) u32    u32x4;
typedef __attribute__((ext_vector_type(2))) u32    u32x2;

__device__ __forceinline__ u16 f2bf(float f) {
  u32 u = __builtin_bit_cast(u32, f);
  u += 0x7fffu + ((u >> 16) & 1u);   // RNE
  return (u16)(u >> 16);
}

__device__ __forceinline__ f32x4 mfma16(u32x4 a, u32x4 b, f32x4 c) {
  return __builtin_amdgcn_mfma_f32_16x16x32_bf16(
      __builtin_bit_cast(bf16x8, a), __builtin_bit_cast(bf16x8, b), c, 0, 0, 0);
}

// ---------------------------------------------------------------------------
// LayerNorm: one row per block (256 thr), f32 in -> bf16 out
// ---------------------------------------------------------------------------
__launch_bounds__(256)
__global__ void ln_kernel(const float* __restrict__ x, const float* __restrict__ g,
                          const float* __restrict__ bv, u16* __restrict__ xn) {
  const int row = blockIdx.x, t = threadIdx.x;
  const float4 v = ((const float4*)(x + (size_t)row * DIM))[t];
  float s  = v.x + v.y + v.z + v.w;
  float ss = v.x * v.x + v.y * v.y + v.z * v.z + v.w * v.w;
#pragma unroll
  for (int m = 32; m; m >>= 1) { s += __shfl_xor(s, m); ss += __shfl_xor(ss, m); }
  __shared__ float red[8];
  if ((t & 63) == 0) { red[(t >> 6) * 2] = s; red[(t >> 6) * 2 + 1] = ss; }
  __syncthreads();
  s  = red[0] + red[2] + red[4] + red[6];
  ss = red[1] + red[3] + red[5] + red[7];
  const float mu  = s * (1.0f / DIM);
  const float var = ss * (1.0f / DIM) - mu * mu;
  const float rs  = rsqrtf(var + 1e-5f);
  const float4 gg = ((const float4*)g)[t];
  const float4 bb = ((const float4*)bv)[t];
  ushort4 o;
  o.x = f2bf((v.x - mu) * rs * gg.x + bb.x);
  o.y = f2bf((v.y - mu) * rs * gg.y + bb.y);
  o.z = f2bf((v.z - mu) * rs * gg.z + bb.z);
  o.w = f2bf((v.w - mu) * rs * gg.w + bb.w);
  ((ushort4*)(xn + (size_t)row * DIM))[t] = o;
}

// ---------------------------------------------------------------------------
// Weight convert+transpose: W f32 [K][N] -> WT bf16 [N][K]; 32x32 tiles
// ---------------------------------------------------------------------------
__launch_bounds__(256)
__global__ void wcvt_t(const float* __restrict__ W, u16* __restrict__ WT, int K, int N) {
  __shared__ float tile[32][33];
  const int t = threadIdx.x;
  const int k0 = blockIdx.x * 32, n0 = blockIdx.y * 32;
  {
    int ki = t >> 3, nq = t & 7;
    const float4 v = *(const float4*)(W + (size_t)(k0 + ki) * N + n0 + nq * 4);
    tile[ki][nq * 4 + 0] = v.x; tile[ki][nq * 4 + 1] = v.y;
    tile[ki][nq * 4 + 2] = v.z; tile[ki][nq * 4 + 3] = v.w;
  }
  __syncthreads();
  {
    int ni = t >> 3, kq = t & 7;
    ushort4 o;
    o.x = f2bf(tile[kq * 4 + 0][ni]); o.y = f2bf(tile[kq * 4 + 1][ni]);
    o.z = f2bf(tile[kq * 4 + 2][ni]); o.w = f2bf(tile[kq * 4 + 3][ni]);
    *(ushort4*)(WT + (size_t)(n0 + ni) * K + k0 + kq * 4) = o;
  }
}

// ---------------------------------------------------------------------------
// V transpose: VT[b][g][d][n] <- kv[b][n][1024 + g*64 + d]
// ---------------------------------------------------------------------------
__launch_bounds__(256)
__global__ void v_transpose(const u16* __restrict__ kv, u16* __restrict__ VT) {
  __shared__ u16 tile[32][72];       // 32 n x 64 d (+8 pad)
  const int t = threadIdx.x;
  const int n0 = blockIdx.x * 32, gh = blockIdx.y, b = blockIdx.z;
  {
    int i = t >> 3, dq = t & 7;
    u32x4 v = *(const u32x4*)(kv + ((size_t)(b * NSEQ + n0 + i)) * (2 * DIM)
                              + DIM + gh * DH + dq * 8);
    *(u32x4*)(&tile[i][dq * 8]) = v;   // byte off = i*144 + dq*16, 16B aligned
  }
  __syncthreads();
  {
    int d = t >> 2, nq = t & 3;
    u32x4 ov;
    ov.x = (u32)tile[nq * 8 + 0][d] | ((u32)tile[nq * 8 + 1][d] << 16);
    ov.y = (u32)tile[nq * 8 + 2][d] | ((u32)tile[nq * 8 + 3][d] << 16);
    ov.z = (u32)tile[nq * 8 + 4][d] | ((u32)tile[nq * 8 + 5][d] << 16);
    ov.w = (u32)tile[nq * 8 + 6][d] | ((u32)tile[nq * 8 + 7][d] << 16);
    *(u32x4*)(VT + ((size_t)((b * NH + gh) * DH + d)) * NSEQ + n0 + nq * 8) = ov;
  }
}

// ---------------------------------------------------------------------------
// GEMM: C[M][N] = A[M][K](bf16) * BT[N][K](bf16)^T, 128x128 tile, BK=32,
// 4 waves (2x2), reg-staged LDS, b128 frag reads, shared k-rule k = 8*q + e.
// ---------------------------------------------------------------------------
template<int OUTF32, int BIAS>
__launch_bounds__(256)
__global__ void gemm_bt(const u16* __restrict__ A, const u16* __restrict__ BT,
                        void* __restrict__ Cp, const float* __restrict__ bias,
                        float alpha, int M, int N, int K) {
  __shared__ u16 As[128 * 32];
  __shared__ u16 Bs[128 * 32];
  const int t = threadIdx.x, w = t >> 6, lane = t & 63, r = lane & 15, q = lane >> 4;
  const int m0 = blockIdx.x * 128, n0 = blockIdx.y * 128;
  (void)w;
  f32x4 acc[4][4] = {};
  u32x4 ra[2], rb[2];

  auto loadAB = [&](int k0) {
#pragma unroll
    for (int c = 0; c < 2; c++) {
      int u = t + 256 * c;               // [0,512)
      int row = u >> 2, col = (u & 3) * 8;
      ra[c] = *(const u32x4*)(A  + (size_t)(m0 + row) * K + k0 + col);
      rb[c] = *(const u32x4*)(BT + (size_t)(n0 + row) * K + k0 + col);
    }
  };
  auto storeAB = [&]() {
#pragma unroll
    for (int c = 0; c < 2; c++) {
      int u = t + 256 * c;
      int row = u >> 2, col = (u & 3) * 8;
      *(u32x4*)(As + row * 32 + col) = ra[c];
      *(u32x4*)(Bs + row * 32 + col) = rb[c];
    }
  };

  loadAB(0);
  const int wr = (t >> 7) * 64;          // wave row block (waves 2x2)
  const int wc = ((t >> 6) & 1) * 64;    // wave col block
  for (int k0 = 0; k0 < K; k0 += 32) {
    storeAB();
    __syncthreads();
    if (k0 + 32 < K) loadAB(k0 + 32);
    u32x4 af[4], bf[4];
#pragma unroll
    for (int mc = 0; mc < 4; mc++)
      af[mc] = *(const u32x4*)(As + (wr + mc * 16 + r) * 32 + q * 8);
#pragma unroll
    for (int nc = 0; nc < 4; nc++)
      bf[nc] = *(const u32x4*)(Bs + (wc + nc * 16 + r) * 32 + q * 8);
#pragma unroll
    for (int mc = 0; mc < 4; mc++)
#pragma unroll
      for (int nc = 0; nc < 4; nc++)
        acc[mc][nc] = mfma16(af[mc], bf[nc], acc[mc][nc]);
    __syncthreads();
  }
#pragma unroll
  for (int mc = 0; mc < 4; mc++) {
#pragma unroll
    for (int nc = 0; nc < 4; nc++) {
#pragma unroll
      for (int e = 0; e < 4; e++) {
        int row = m0 + wr + mc * 16 + q * 4 + e;   // D row = (l>>4)*4+e  [m89]
        int col = n0 + wc + nc * 16 + r;           // D col = l&15
        float v = acc[mc][nc][e] * alpha;
        if (BIAS) v += bias[col];
        if (OUTF32) ((float*)Cp)[(size_t)row * N + col] = v;
        else        ((u16*)Cp)[(size_t)row * N + col]   = f2bf(v);
      }
    }
  }
}

// ---------------------------------------------------------------------------
// Fused attention. PASSB=0: row sums l[g,i]; PASSB=1: output accumulation.
// WG: 16 waves, 16 query rows (i = i0 + w per wave), sweep all 2048 j in 32-tiles.
// ---------------------------------------------------------------------------
template<int PASSB>
__launch_bounds__(1024, 4)
__global__ void attn_kernel(const u16* __restrict__ qb, const u16* __restrict__ kvb,
                            const u16* __restrict__ vtb,
                            const float* __restrict__ mixpre, const float* __restrict__ mixpost,
                            float* __restrict__ lglob, u16* __restrict__ oattn) {
  // S/P2: 32 chunks (c = i*32+j, chunk = 2*i+jc), per-chunk 16h x 16c blocked, stride 260
  __shared__ u16 Sb [32 * 260];
  __shared__ u16 P2b[32 * 260];
  __shared__ u16 P3b[16 * 580];      // [g'][i(16) x jstride36] + 4 pad per g'
  const int t = threadIdx.x;
  const int w = t >> 6, lane = t & 63, r = lane & 15, qd = lane >> 4;
  const int bid = blockIdx.x;
  // XCD swizzle: each XCD sees one batch's K/V (perf only)
  const int xcd  = bid & 7;
  const int b    = xcd & 1;
  const int iblk = ((xcd >> 1) << 5) + (bid >> 3);   // [0,128)
  const int i0   = iblk << 4;

  // Q B-frags (head w, rows i0..i0+15): B[k=d][n=i], rule d = kc*32 + 8*qd + e
  u32x4 qf[2];
#pragma unroll
  for (int kc = 0; kc < 2; kc++)
    qf[kc] = *(const u32x4*)(qb + ((size_t)(b * NSEQ + i0 + r)) * DIM
                             + w * DH + kc * 32 + qd * 8);

  // Mix-matrix B-frags, pre-halved, duplicated k-halves: B[k=h][n=g],
  // h = 4*qd + (e&3)  (each h appears twice across the 32 k-positions -> *0.5)
  u32x4 mp1, mp2;
  {
    u16 c0 = f2bf(0.5f * mixpre[(4 * qd + 0) * 16 + r]);
    u16 c1 = f2bf(0.5f * mixpre[(4 * qd + 1) * 16 + r]);
    u16 c2 = f2bf(0.5f * mixpre[(4 * qd + 2) * 16 + r]);
    u16 c3 = f2bf(0.5f * mixpre[(4 * qd + 3) * 16 + r]);
    mp1.x = (u32)c0 | ((u32)c1 << 16);
    mp1.y = (u32)c2 | ((u32)c3 << 16);
    mp1.z = mp1.x; mp1.w = mp1.y;
    u16 d0 = f2bf(0.5f * mixpost[(4 * qd + 0) * 16 + r]);
    u16 d1 = f2bf(0.5f * mixpost[(4 * qd + 1) * 16 + r]);
    u16 d2_ = f2bf(0.5f * mixpost[(4 * qd + 2) * 16 + r]);
    u16 d3_ = f2bf(0.5f * mixpost[(4 * qd + 3) * 16 + r]);
    mp2.x = (u32)d0 | ((u32)d1 << 16);
    mp2.y = (u32)d2_ | ((u32)d3_ << 16);
    mp2.z = mp2.x; mp2.w = mp2.y;
  }

  const f32x4 zero4 = {0.0f, 0.0f, 0.0f, 0.0f};
  float rl = 0.0f, lpart = 0.0f;
  if (PASSB) rl = 1.0f / lglob[((size_t)(b * NH + r)) * NSEQ + i0 + w];
  f32x4 oacc[4];
#pragma unroll
  for (int dc = 0; dc < 4; dc++) oacc[dc] = zero4;

  for (int s = 0; s < NSEQ / 32; s++) {
    const int jstep = s * 32;
    // ---- PH1: QK^T swapped (A=K: m=j, B=Q: n=i). D row=j-quad, col=i.
#pragma unroll
    for (int jc = 0; jc < 2; jc++) {
      const u16* krow = kvb + ((size_t)(b * NSEQ + jstep + jc * 16 + r)) * (2 * DIM)
                        + w * DH + qd * 8;
      u32x4 kf0 = *(const u32x4*)(krow);
      u32x4 kf1 = *(const u32x4*)(krow + 32);
      f32x4 sac = mfma16(kf0, qf[0], zero4);
      sac = mfma16(kf1, qf[1], sac);
      // write S^T[h=w] at (i=r, j=jc*16+4*qd+e): chunk=2r+jc, in-block h*16+c_lo
      u32x2 pk;
      pk.x = (u32)f2bf(sac[0]) | ((u32)f2bf(sac[1]) << 16);
      pk.y = (u32)f2bf(sac[2]) | ((u32)f2bf(sac[3]) << 16);
      *(u32x2*)(Sb + (2 * r + jc) * 260 + w * 16 + 4 * qd) = pk;
    }
    __syncthreads();   // bar1: S tiles complete (cross-wave)

    // ---- PH2: mix_pre. Wave w owns chunks {2w, 2w+1} (i = w).
    // A[m=c_lo][k=h]: lane reads Sb[ch][h=4qd+e][c_lo=r], dup halves.
    f32x4 d2v[2];
#pragma unroll
    for (int jc = 0; jc < 2; jc++) {
      const int ch = 2 * w + jc;
      u16 a0 = Sb[ch * 260 + (4 * qd + 0) * 16 + r];
      u16 a1 = Sb[ch * 260 + (4 * qd + 1) * 16 + r];
      u16 a2 = Sb[ch * 260 + (4 * qd + 2) * 16 + r];
      u16 a3 = Sb[ch * 260 + (4 * qd + 3) * 16 + r];
      u32x4 af;
      af.x = (u32)a0 | ((u32)a1 << 16);
      af.y = (u32)a2 | ((u32)a3 << 16);
      af.z = af.x; af.w = af.y;
      d2v[jc] = mfma16(af, mp1, zero4);   // D2 row=c_lo(4qd+e), col=g(r)
    }

    if (!PASSB) {
#pragma unroll
      for (int jc = 0; jc < 2; jc++)
#pragma unroll
        for (int e = 0; e < 4; e++)
          lpart += exp2f((d2v[jc][e] - MHAT) * L2E);
      __syncthreads();   // protect Sb before next-iter write
    } else {
      // P2 = exp(S2-8)/l  (normalized attn, pre-mixpost), chunk is wave-local
#pragma unroll
      for (int jc = 0; jc < 2; jc++) {
        u16 p0 = f2bf(exp2f((d2v[jc][0] - MHAT) * L2E) * rl);
        u16 p1 = f2bf(exp2f((d2v[jc][1] - MHAT) * L2E) * rl);
        u16 p2_ = f2bf(exp2f((d2v[jc][2] - MHAT) * L2E) * rl);
        u16 p3_ = f2bf(exp2f((d2v[jc][3] - MHAT) * L2E) * rl);
        u32x2 pk;
        pk.x = (u32)p0 | ((u32)p1 << 16);
        pk.y = (u32)p2_ | ((u32)p3_ << 16);
        *(u32x2*)(P2b + (2 * w + jc) * 260 + r * 16 + 4 * qd) = pk;
      }
      // ---- PH3: mix_post (P2 chunk written & read by this same wave; lgkmcnt only)
#pragma unroll
      for (int jc = 0; jc < 2; jc++) {
        const int ch = 2 * w + jc;
        u16 a0 = P2b[ch * 260 + (4 * qd + 0) * 16 + r];
        u16 a1 = P2b[ch * 260 + (4 * qd + 1) * 16 + r];
        u16 a2 = P2b[ch * 260 + (4 * qd + 2) * 16 + r];
        u16 a3 = P2b[ch * 260 + (4 * qd + 3) * 16 + r];
        u32x4 af;
        af.x = (u32)a0 | ((u32)a1 << 16);
        af.y = (u32)a2 | ((u32)a3 << 16);
        af.z = af.x; af.w = af.y;
        f32x4 d3 = mfma16(af, mp2, zero4);  // row=c_lo, col=g'(r)
        // write P3[g'=r][i=w][j=jc*16+4qd+e]
        u32x2 pk;
        pk.x = (u32)f2bf(d3[0]) | ((u32)f2bf(d3[1]) << 16);
        pk.y = (u32)f2bf(d3[2]) | ((u32)f2bf(d3[3]) << 16);
        *(u32x2*)(P3b + r * 580 + w * 36 + jc * 16 + 4 * qd) = pk;
      }
      __syncthreads();   // bar2: P3 complete (cross-wave)
      // ---- PH4: PV. Wave w = head g'. A[m=i][k=j], rule j = 8*qd + e.
      u32x2 lo = *(const u32x2*)(P3b + w * 580 + r * 36 + 8 * qd);
      u32x2 hi = *(const u32x2*)(P3b + w * 580 + r * 36 + 8 * qd + 4);
      u32x4 paf; paf.x = lo.x; paf.y = lo.y; paf.z = hi.x; paf.w = hi.y;
#pragma unroll
      for (int dc = 0; dc < 4; dc++) {
        u32x4 bfv = *(const u32x4*)(vtb + ((size_t)((b * NH + w) * DH + dc * 16 + r)) * NSEQ
                                    + jstep + 8 * qd);
        oacc[dc] = mfma16(paf, bfv, oacc[dc]);
      }
      // no barrier: PH4 P3-reads vs next PH3-writes separated by next bar1.
    }
  }

  if (!PASSB) {
    lpart += __shfl_xor(lpart, 16);
    lpart += __shfl_xor(lpart, 32);
    if (qd == 0) lglob[((size_t)(b * NH + r)) * NSEQ + i0 + w] = lpart;
  } else {
#pragma unroll
    for (int dc = 0; dc < 4; dc++)
#pragma unroll
      for (int e = 0; e < 4; e++)
        oattn[((size_t)(b * NSEQ + i0 + 4 * qd + e)) * DIM + w * DH + dc * 16 + r]
            = f2bf(oacc[dc][e]);
  }
}

// ---------------------------------------------------------------------------
extern "C" void kernel_launch(void* const* d_in, const int* in_sizes, int n_in,
                              void* d_out, int out_size, void* d_ws, size_t ws_size,
                              hipStream_t stream) {
  (void)in_sizes; (void)n_in; (void)out_size; (void)ws_size;
  const float* x       = (const float*)d_in[0];
  const float* ln_g    = (const float*)d_in[1];
  const float* ln_b    = (const float*)d_in[2];
  const float* Wq      = (const float*)d_in[3];
  const float* Wkv     = (const float*)d_in[4];
  const float* mixpre  = (const float*)d_in[5];
  const float* mixpost = (const float*)d_in[6];
  const float* Wout    = (const float*)d_in[7];
  const float* bout    = (const float*)d_in[8];
  float* out = (float*)d_out;

  char* p = (char*)d_ws;
  auto alloc = [&](size_t bytes) {
    char* rp = p; p += (bytes + 255) & ~(size_t)255; return rp;
  };
  u16*   xn    = (u16*)alloc((size_t)4096 * 1024 * 2);
  u16*   WqT   = (u16*)alloc((size_t)1024 * 1024 * 2);
  u16*   WkvT  = (u16*)alloc((size_t)2048 * 1024 * 2);
  u16*   WoutT = (u16*)alloc((size_t)1024 * 1024 * 2);
  u16*   qb    = (u16*)alloc((size_t)4096 * 1024 * 2);
  u16*   kvb   = (u16*)alloc((size_t)4096 * 2048 * 2);
  u16*   VTb   = (u16*)alloc((size_t)2 * NH * DH * NSEQ * 2);
  float* lg    = (float*)alloc((size_t)2 * NH * NSEQ * 4);
  u16*   oat   = (u16*)alloc((size_t)4096 * 1024 * 2);

  ln_kernel<<<4096, 256, 0, stream>>>(x, ln_g, ln_b, xn);
  wcvt_t<<<dim3(32, 32), 256, 0, stream>>>(Wq,   WqT,   1024, 1024);
  wcvt_t<<<dim3(32, 64), 256, 0, stream>>>(Wkv,  WkvT,  1024, 2048);
  wcvt_t<<<dim3(32, 32), 256, 0, stream>>>(Wout, WoutT, 1024, 1024);
  // q pre-scaled by 1/sqrt(64) = 0.125
  gemm_bt<0, 0><<<dim3(32, 8),  256, 0, stream>>>(xn, WqT,  qb,  nullptr, 0.125f, 4096, 1024, 1024);
  gemm_bt<0, 0><<<dim3(32, 16), 256, 0, stream>>>(xn, WkvT, kvb, nullptr, 1.0f,   4096, 2048, 1024);
  v_transpose<<<dim3(64, 16, 2), 256, 0, stream>>>(kvb, VTb);
  attn_kernel<0><<<256, 1024, 0, stream>>>(qb, kvb, VTb, mixpre, mixpost, lg, oat);
  attn_kernel<1><<<256, 1024, 0, stream>>>(qb, kvb, VTb, mixpre, mixpost, lg, oat);
  gemm_bt<1, 1><<<dim3(32, 8), 256, 0, stream>>>(oat, WoutT, out, bout, 1.0f, 4096, 1024, 1024);
}

// Round 3
// 547.053 us; speedup vs baseline: 1.1826x; 1.1826x over previous
//
#include <hip/hip_runtime.h>

// ============================================================================
// Talking-heads attention, MI355X bf16-MFMA, v3 (two-pass attn, correct V-head)
//
//  out[g,i,d] = sum_j (sum_h mp2[h,g] * e[h,i,j]/l[h,i]) * v[g,j,d]
//  -> mix_post MUST be applied to P before PV (V head = output head).
//
//  1. ln_kernel       : x(f32) -> xn(bf16)
//  2. wcvt_t x3       : W(f32)[K][N] -> WT(bf16)[N][K]
//  3. gemm_bt         : q  = xn @ Wq * 0.125
//  4. gemm_bt         : kv = xn @ Wkv
//  5. v_transpose     : VT[b][g][d][n] <- kv[:, 1024+g*64+d]
//  6. attn_v3<0>      : l_part[jh,b,g,i] = sum_{j in half} exp(S2-8)
//  7. attn_v3<1>      : P=e/l -> mix_post MFMA -> PV(V[g']) -> U_part f32
//  8. combine         : oat = bf16(U_part[jh=0] + U_part[jh=1])
//  9. gemm_bt<f32,b>  : d_out = oat @ Wout + bout
//
// attn_v3: 512 WGs (128 i-tiles x b x jh) x 8 waves. Wave owns heads {2w,2w+1}.
//  S layout: [chunk(i,jc)][j16][granule2][head8], granule XOR-swizzled; PH1
//  packs head pairs into b32 writes. Mix MFMAs use dup-half positional k-rule
//  (A and B share packing -> HW k-map irrelevant; validated in v1).
// ============================================================================

#define NSEQ 2048
#define DIM  1024
#define NH   16
#define DH   64
#define L2E  1.4426950408889634f
#define MH2  11.541560327111708f   /* 8 * log2(e) */

typedef unsigned short u16;
typedef unsigned int   u32;
typedef __attribute__((ext_vector_type(4))) float  f32x4;
typedef __attribute__((ext_vector_type(8))) __bf16 bf16x8;
typedef __attribute__((ext_vector_type(4))) u32    u32x4;
typedef __attribute__((ext_vector_type(2))) u32    u32x2;

__device__ __forceinline__ u16 f2bf(float f) {
  u32 u = __builtin_bit_cast(u32, f);
  u += 0x7fffu + ((u >> 16) & 1u);   // RNE
  return (u16)(u >> 16);
}

__device__ __forceinline__ f32x4 mfma16(u32x4 a, u32x4 b, f32x4 c) {
  return __builtin_amdgcn_mfma_f32_16x16x32_bf16(
      __builtin_bit_cast(bf16x8, a), __builtin_bit_cast(bf16x8, b), c, 0, 0, 0);
}

// ---------------------------------------------------------------------------
// LayerNorm: one row per block (256 thr), f32 in -> bf16 out
// ---------------------------------------------------------------------------
__launch_bounds__(256)
__global__ void ln_kernel(const float* __restrict__ x, const float* __restrict__ g,
                          const float* __restrict__ bv, u16* __restrict__ xn) {
  const int row = blockIdx.x, t = threadIdx.x;
  const float4 v = ((const float4*)(x + (size_t)row * DIM))[t];
  float s  = v.x + v.y + v.z + v.w;
  float ss = v.x * v.x + v.y * v.y + v.z * v.z + v.w * v.w;
#pragma unroll
  for (int m = 32; m; m >>= 1) { s += __shfl_xor(s, m); ss += __shfl_xor(ss, m); }
  __shared__ float red[8];
  if ((t & 63) == 0) { red[(t >> 6) * 2] = s; red[(t >> 6) * 2 + 1] = ss; }
  __syncthreads();
  s  = red[0] + red[2] + red[4] + red[6];
  ss = red[1] + red[3] + red[5] + red[7];
  const float mu  = s * (1.0f / DIM);
  const float var = ss * (1.0f / DIM) - mu * mu;
  const float rs  = rsqrtf(var + 1e-5f);
  const float4 gg = ((const float4*)g)[t];
  const float4 bb = ((const float4*)bv)[t];
  ushort4 o;
  o.x = f2bf((v.x - mu) * rs * gg.x + bb.x);
  o.y = f2bf((v.y - mu) * rs * gg.y + bb.y);
  o.z = f2bf((v.z - mu) * rs * gg.z + bb.z);
  o.w = f2bf((v.w - mu) * rs * gg.w + bb.w);
  ((ushort4*)(xn + (size_t)row * DIM))[t] = o;
}

// ---------------------------------------------------------------------------
// Weight convert+transpose: W f32 [K][N] -> WT bf16 [N][K]; 32x32 tiles
// ---------------------------------------------------------------------------
__launch_bounds__(256)
__global__ void wcvt_t(const float* __restrict__ W, u16* __restrict__ WT, int K, int N) {
  __shared__ float tile[32][33];
  const int t = threadIdx.x;
  const int k0 = blockIdx.x * 32, n0 = blockIdx.y * 32;
  {
    int ki = t >> 3, nq = t & 7;
    const float4 v = *(const float4*)(W + (size_t)(k0 + ki) * N + n0 + nq * 4);
    tile[ki][nq * 4 + 0] = v.x; tile[ki][nq * 4 + 1] = v.y;
    tile[ki][nq * 4 + 2] = v.z; tile[ki][nq * 4 + 3] = v.w;
  }
  __syncthreads();
  {
    int ni = t >> 3, kq = t & 7;
    ushort4 o;
    o.x = f2bf(tile[kq * 4 + 0][ni]); o.y = f2bf(tile[kq * 4 + 1][ni]);
    o.z = f2bf(tile[kq * 4 + 2][ni]); o.w = f2bf(tile[kq * 4 + 3][ni]);
    *(ushort4*)(WT + (size_t)(n0 + ni) * K + k0 + kq * 4) = o;
  }
}

// ---------------------------------------------------------------------------
// V transpose: VT[b][g][d][n] <- kv[b][n][1024 + g*64 + d]
// ---------------------------------------------------------------------------
__launch_bounds__(256)
__global__ void v_transpose(const u16* __restrict__ kv, u16* __restrict__ VT) {
  __shared__ u16 tile[32][72];
  const int t = threadIdx.x;
  const int n0 = blockIdx.x * 32, gh = blockIdx.y, b = blockIdx.z;
  {
    int i = t >> 3, dq = t & 7;
    u32x4 v = *(const u32x4*)(kv + ((size_t)(b * NSEQ + n0 + i)) * (2 * DIM)
                              + DIM + gh * DH + dq * 8);
    *(u32x4*)(&tile[i][dq * 8]) = v;
  }
  __syncthreads();
  {
    int d = t >> 2, nq = t & 3;
    u32x4 ov;
    ov.x = (u32)tile[nq * 8 + 0][d] | ((u32)tile[nq * 8 + 1][d] << 16);
    ov.y = (u32)tile[nq * 8 + 2][d] | ((u32)tile[nq * 8 + 3][d] << 16);
    ov.z = (u32)tile[nq * 8 + 4][d] | ((u32)tile[nq * 8 + 5][d] << 16);
    ov.w = (u32)tile[nq * 8 + 6][d] | ((u32)tile[nq * 8 + 7][d] << 16);
    *(u32x4*)(VT + ((size_t)((b * NH + gh) * DH + d)) * NSEQ + n0 + nq * 8) = ov;
  }
}

// ---------------------------------------------------------------------------
// GEMM: C[M][N] = A[M][K](bf16) * BT[N][K]^T, 128x128 tile, BK=32, 4 waves
// ---------------------------------------------------------------------------
template<int OUTF32, int BIAS>
__launch_bounds__(256)
__global__ void gemm_bt(const u16* __restrict__ A, const u16* __restrict__ BT,
                        void* __restrict__ Cp, const float* __restrict__ bias,
                        float alpha, int M, int N, int K) {
  __shared__ u16 As[128 * 32];
  __shared__ u16 Bs[128 * 32];
  const int t = threadIdx.x, lane = t & 63, r = lane & 15, q = lane >> 4;
  const int m0 = blockIdx.x * 128, n0 = blockIdx.y * 128;
  f32x4 acc[4][4] = {};
  u32x4 ra[2], rb[2];

  auto loadAB = [&](int k0) {
#pragma unroll
    for (int c = 0; c < 2; c++) {
      int u = t + 256 * c;
      int row = u >> 2, col = (u & 3) * 8;
      ra[c] = *(const u32x4*)(A  + (size_t)(m0 + row) * K + k0 + col);
      rb[c] = *(const u32x4*)(BT + (size_t)(n0 + row) * K + k0 + col);
    }
  };
  auto storeAB = [&]() {
#pragma unroll
    for (int c = 0; c < 2; c++) {
      int u = t + 256 * c;
      int row = u >> 2, col = (u & 3) * 8;
      *(u32x4*)(As + row * 32 + col) = ra[c];
      *(u32x4*)(Bs + row * 32 + col) = rb[c];
    }
  };

  loadAB(0);
  const int wr = (t >> 7) * 64;
  const int wc = ((t >> 6) & 1) * 64;
  for (int k0 = 0; k0 < K; k0 += 32) {
    storeAB();
    __syncthreads();
    if (k0 + 32 < K) loadAB(k0 + 32);
    u32x4 af[4], bf[4];
#pragma unroll
    for (int mc = 0; mc < 4; mc++)
      af[mc] = *(const u32x4*)(As + (wr + mc * 16 + r) * 32 + q * 8);
#pragma unroll
    for (int nc = 0; nc < 4; nc++)
      bf[nc] = *(const u32x4*)(Bs + (wc + nc * 16 + r) * 32 + q * 8);
#pragma unroll
    for (int mc = 0; mc < 4; mc++)
#pragma unroll
      for (int nc = 0; nc < 4; nc++)
        acc[mc][nc] = mfma16(af[mc], bf[nc], acc[mc][nc]);
    __syncthreads();
  }
#pragma unroll
  for (int mc = 0; mc < 4; mc++) {
#pragma unroll
    for (int nc = 0; nc < 4; nc++) {
#pragma unroll
      for (int e = 0; e < 4; e++) {
        int row = m0 + wr + mc * 16 + q * 4 + e;
        int col = n0 + wc + nc * 16 + r;
        float v = acc[mc][nc][e] * alpha;
        if (BIAS) v += bias[col];
        if (OUTF32) ((float*)Cp)[(size_t)row * N + col] = v;
        else        ((u16*)Cp)[(size_t)row * N + col]   = f2bf(v);
      }
    }
  }
}

// ---------------------------------------------------------------------------
// attn_v3<PASSB>: 512 WGs (128 i-tiles x b x jh), 8 waves; wave owns heads
// {2w, 2w+1}. PASSB=0: l_part row sums. PASSB=1: normalized P -> mix_post
// MFMA -> PV with V[g'] -> U_part f32 partials.
// ---------------------------------------------------------------------------
template<int PASSB>
__launch_bounds__(512, 4)
__global__ void attn_v3(const u16* __restrict__ qb, const u16* __restrict__ kvb,
                        const u16* __restrict__ vtb,
                        const float* __restrict__ mixpre, const float* __restrict__ mixpost,
                        float* __restrict__ l_part, float* __restrict__ U_part) {
  // S/e: [32 chunks][16 j][2 gran][8 h] u16, chunk stride 264 (16B-aligned pad)
  __shared__ u16 Sb[32 * 264];
  __shared__ u16 P3b[PASSB ? 16 * 648 : 16];   // [g'][16 i][32 j + 8 pad]
  const int t = threadIdx.x, w = t >> 6, lane = t & 63, r = lane & 15, qd = lane >> 4;
  const int bid = blockIdx.x;
  const int jh = bid & 1, b = (bid >> 1) & 1;   // XCD x serves slab (jh,b)=x&3
  const int i0 = (bid >> 2) << 4;
  const f32x4 zero4 = {0.0f, 0.0f, 0.0f, 0.0f};

  // Q A-frags (A[m=i][k=d], pos rule d = kc*32 + 8qd + e), heads 2w+hh
  u32x4 qf[2][2];
#pragma unroll
  for (int hh = 0; hh < 2; hh++)
#pragma unroll
    for (int kc = 0; kc < 2; kc++)
      qf[hh][kc] = *(const u32x4*)(qb + ((size_t)(b * NSEQ + i0 + r)) * DIM
                                   + (2 * w + hh) * DH + kc * 32 + qd * 8);

  // mix B-frags, dup-half pos rule: elem e <-> h = 8*(qd&1)+e (each h twice -> *0.5)
  auto build_mix = [&](const float* m) {
    u32x4 f;
    u16 c[8];
#pragma unroll
    for (int e = 0; e < 8; e++)
      c[e] = f2bf(0.5f * m[(8 * (qd & 1) + e) * NH + r]);
    f.x = (u32)c[0] | ((u32)c[1] << 16);
    f.y = (u32)c[2] | ((u32)c[3] << 16);
    f.z = (u32)c[4] | ((u32)c[5] << 16);
    f.w = (u32)c[6] | ((u32)c[7] << 16);
    return f;
  };
  const u32x4 mpf = build_mix(mixpre);
  u32x4 mpostf = {0, 0, 0, 0};
  float rl[2] = {0.0f, 0.0f};
  if (PASSB) {
    mpostf = build_mix(mixpost);
    // 1/l for (head g=r, i = i0+2w+ii): sum of both j-half partials
#pragma unroll
    for (int ii = 0; ii < 2; ii++) {
      int ig = i0 + 2 * w + ii;
      float lv = l_part[((size_t)(b * NH + r)) * NSEQ + ig]
               + l_part[((size_t)((2 + b) * NH + r)) * NSEQ + ig];
      rl[ii] = 1.0f / lv;
    }
  }

  f32x4 U[2][4];
#pragma unroll
  for (int hh = 0; hh < 2; hh++)
#pragma unroll
    for (int dc = 0; dc < 4; dc++) U[hh][dc] = zero4;
  float lsum0 = 0.0f, lsum1 = 0.0f;

  for (int s = 0; s < 32; s++) {
    const int j0 = jh * 1024 + s * 32;
    // ---- PH1: QK^T (A=Q m=i, B=K n=j). Lane reg e: (i=4qd+e, j=r).
    const int gran = (w >> 2) ^ ((r >> 2) & 1) ^ (qd & 1);
#pragma unroll
    for (int jc = 0; jc < 2; jc++) {
      f32x4 sh[2];
#pragma unroll
      for (int hh = 0; hh < 2; hh++) {
        const u16* kr = kvb + ((size_t)(b * NSEQ + j0 + jc * 16 + r)) * (2 * DIM)
                        + (2 * w + hh) * DH + qd * 8;
        u32x4 kf0 = *(const u32x4*)(kr);
        u32x4 kf1 = *(const u32x4*)(kr + 32);
        sh[hh] = mfma16(qf[hh][0], kf0, zero4);
        sh[hh] = mfma16(qf[hh][1], kf1, sh[hh]);
      }
#pragma unroll
      for (int e = 0; e < 4; e++) {
        u32 pk = (u32)f2bf(sh[0][e]) | ((u32)f2bf(sh[1][e]) << 16);
        *(u32*)(Sb + (2 * (4 * qd + e) + jc) * 264 + r * 16 + gran * 8 + 2 * (w & 3)) = pk;
      }
    }
    __syncthreads();   // bar1: S complete (cross-wave)

    // ---- PH2(+PH3): mix_pre -> exp (-> normalize, e-write, mix_post, P3)
#pragma unroll
    for (int cc = 0; cc < 4; cc++) {
      const int ch = 4 * w + cc, ii = cc >> 1, jc = cc & 1;
      const int gs = (qd & 1) ^ ((r >> 2) & 1) ^ ((ch >> 3) & 1);
      u32x4 af = *(const u32x4*)(Sb + ch * 264 + r * 16 + gs * 8);
      f32x4 d2 = mfma16(af, mpf, zero4);   // D2[j=4qd+e][g=r]
      float p0 = exp2f(fmaf(d2[0], L2E, -MH2));
      float p1 = exp2f(fmaf(d2[1], L2E, -MH2));
      float p2 = exp2f(fmaf(d2[2], L2E, -MH2));
      float p3 = exp2f(fmaf(d2[3], L2E, -MH2));
      if (!PASSB) {
        if (ii == 0) lsum0 += (p0 + p1) + (p2 + p3);
        else         lsum1 += (p0 + p1) + (p2 + p3);
      } else {
        // normalized P = e/l (f32), write back to same chunk layout (wave-local)
        const float sc = rl[ii];
        const int granw = (r >> 3) ^ (qd & 1) ^ ((ch >> 3) & 1);
        Sb[ch * 264 + (4 * qd + 0) * 16 + granw * 8 + (r & 7)] = f2bf(p0 * sc);
        Sb[ch * 264 + (4 * qd + 1) * 16 + granw * 8 + (r & 7)] = f2bf(p1 * sc);
        Sb[ch * 264 + (4 * qd + 2) * 16 + granw * 8 + (r & 7)] = f2bf(p2 * sc);
        Sb[ch * 264 + (4 * qd + 3) * 16 + granw * 8 + (r & 7)] = f2bf(p3 * sc);
        // PH3: mix_post (same-wave DS ordering: write precedes read in DS pipe)
        u32x4 ef = *(const u32x4*)(Sb + ch * 264 + r * 16 + gs * 8);
        f32x4 d3 = mfma16(ef, mpostf, zero4);   // D3[j=4qd+e][g'=r]
        const int i = 2 * w + ii;
        u32x2 pk;
        pk.x = (u32)f2bf(d3[0]) | ((u32)f2bf(d3[1]) << 16);
        pk.y = (u32)f2bf(d3[2]) | ((u32)f2bf(d3[3]) << 16);
        *(u32x2*)(P3b + r * 648 + i * 40 + jc * 16 + 4 * qd) = pk;
      }
    }
    __syncthreads();   // bar2: P3 complete / Sb reads drained before next PH1

    if (PASSB) {
      // ---- PH4: PV, heads g' = {2w, 2w+1}. A[m=i=r][k=j=8qd+e], B = VT.
#pragma unroll
      for (int hh = 0; hh < 2; hh++) {
        const int g = 2 * w + hh;
        u32x4 paf = *(const u32x4*)(P3b + g * 648 + r * 40 + 8 * qd);
#pragma unroll
        for (int dc = 0; dc < 4; dc++) {
          u32x4 vf = *(const u32x4*)(vtb
              + ((size_t)((b * NH + g) * DH + dc * 16 + r)) * NSEQ + j0 + 8 * qd);
          U[hh][dc] = mfma16(paf, vf, U[hh][dc]);
        }
      }
      // PH4 P3-reads drain before next bar1 -> safe vs next PH3 writes
    }
  }

  if (!PASSB) {
    lsum0 += __shfl_xor(lsum0, 16); lsum0 += __shfl_xor(lsum0, 32);
    lsum1 += __shfl_xor(lsum1, 16); lsum1 += __shfl_xor(lsum1, 32);
    if (qd == 0) {
      l_part[((size_t)((jh * 2 + b) * NH + r)) * NSEQ + i0 + 2 * w]     = lsum0;
      l_part[((size_t)((jh * 2 + b) * NH + r)) * NSEQ + i0 + 2 * w + 1] = lsum1;
    }
  } else {
#pragma unroll
    for (int hh = 0; hh < 2; hh++)
#pragma unroll
      for (int dc = 0; dc < 4; dc++)
#pragma unroll
        for (int e = 0; e < 4; e++)
          U_part[((size_t)((jh * 2 + b) * NSEQ + i0 + 4 * qd + e)) * DIM
                 + (2 * w + hh) * DH + dc * 16 + r] = U[hh][dc][e];
  }
}

// ---------------------------------------------------------------------------
// combine: oat = bf16(U_part[slab p] + U_part[slab p+2])  (flat layout)
// ---------------------------------------------------------------------------
__launch_bounds__(256)
__global__ void combine(const float* __restrict__ U, u16* __restrict__ oat) {
  const size_t x = ((size_t)blockIdx.x * 256 + threadIdx.x) * 4;
  float4 a = *(const float4*)(U + x);
  float4 c = *(const float4*)(U + x + (size_t)4 * 1024 * 1024);
  u32x2 pk;
  pk.x = (u32)f2bf(a.x + c.x) | ((u32)f2bf(a.y + c.y) << 16);
  pk.y = (u32)f2bf(a.z + c.z) | ((u32)f2bf(a.w + c.w) << 16);
  *(u32x2*)(oat + x) = pk;
}

// ---------------------------------------------------------------------------
extern "C" void kernel_launch(void* const* d_in, const int* in_sizes, int n_in,
                              void* d_out, int out_size, void* d_ws, size_t ws_size,
                              hipStream_t stream) {
  (void)in_sizes; (void)n_in; (void)out_size; (void)ws_size;
  const float* x       = (const float*)d_in[0];
  const float* ln_g    = (const float*)d_in[1];
  const float* ln_b    = (const float*)d_in[2];
  const float* Wq      = (const float*)d_in[3];
  const float* Wkv     = (const float*)d_in[4];
  const float* mixpre  = (const float*)d_in[5];
  const float* mixpost = (const float*)d_in[6];
  const float* Wout    = (const float*)d_in[7];
  const float* bout    = (const float*)d_in[8];
  float* out = (float*)d_out;

  char* p = (char*)d_ws;
  auto alloc = [&](size_t bytes) {
    char* rp = p; p += (bytes + 255) & ~(size_t)255; return rp;
  };
  u16*   xn    = (u16*)alloc((size_t)4096 * 1024 * 2);
  u16*   WqT   = (u16*)alloc((size_t)1024 * 1024 * 2);
  u16*   WkvT  = (u16*)alloc((size_t)2048 * 1024 * 2);
  u16*   WoutT = (u16*)alloc((size_t)1024 * 1024 * 2);
  u16*   qb    = (u16*)alloc((size_t)4096 * 1024 * 2);
  u16*   kvb   = (u16*)alloc((size_t)4096 * 2048 * 2);
  u16*   VTb   = (u16*)alloc((size_t)2 * NH * DH * NSEQ * 2);
  float* lpart = (float*)alloc((size_t)4 * NH * NSEQ * 4);
  float* Upart = (float*)alloc((size_t)4 * NSEQ * DIM * 4);   // 32 MB
  u16*   oat   = (u16*)alloc((size_t)4096 * 1024 * 2);

  ln_kernel<<<4096, 256, 0, stream>>>(x, ln_g, ln_b, xn);
  wcvt_t<<<dim3(32, 32), 256, 0, stream>>>(Wq,   WqT,   1024, 1024);
  wcvt_t<<<dim3(32, 64), 256, 0, stream>>>(Wkv,  WkvT,  1024, 2048);
  wcvt_t<<<dim3(32, 32), 256, 0, stream>>>(Wout, WoutT, 1024, 1024);
  gemm_bt<0, 0><<<dim3(32, 8),  256, 0, stream>>>(xn, WqT,  qb,  nullptr, 0.125f, 4096, 1024, 1024);
  gemm_bt<0, 0><<<dim3(32, 16), 256, 0, stream>>>(xn, WkvT, kvb, nullptr, 1.0f,   4096, 2048, 1024);
  v_transpose<<<dim3(64, 16, 2), 256, 0, stream>>>(kvb, VTb);
  attn_v3<0><<<512, 512, 0, stream>>>(qb, kvb, VTb, mixpre, mixpost, lpart, Upart);
  attn_v3<1><<<512, 512, 0, stream>>>(qb, kvb, VTb, mixpre, mixpost, lpart, Upart);
  combine<<<4096, 256, 0, stream>>>(Upart, oat);
  gemm_bt<1, 1><<<dim3(32, 8), 256, 0, stream>>>(oat, WoutT, out, bout, 1.0f, 4096, 1024, 1024);
}

// Round 4
// 499.548 us; speedup vs baseline: 1.2950x; 1.0951x over previous
//
#include <hip/hip_runtime.h>

// ============================================================================
// Talking-heads attention, MI355X bf16-MFMA, v4
//
//  out[g,i,d] = sum_j (sum_h mp2[h,g] * e[h,i,j]/l[h,i]) * v[g,j,d]
//
//  1. ln_kernel       : x(f32) -> xn(bf16)
//  2. wcvt_t x3       : W(f32)[K][N] -> WT(bf16)[N][K]
//  3. gemm_bt         : q  = xn @ Wq * 0.125
//  4. gemm_bt         : kv = xn @ Wkv
//  5. v_transpose     : VT[b][g][d][n] <- kv[:, 1024+g*64+d]
//  6. attn_a          : l_part[jq,b,g,i] = sum_{j in quarter} exp(S2-8)
//                       (i-tile 32, 16 steps, K-prefetch, XCD-pinned slabs)
//  7. attn_b          : recompute S2 -> P=e/l (regs) -> mix_post (regs!) ->
//                       P3 LDS -> PV(V[g']) -> U_part f32   (i-tile 16)
//  8. combine         : oat = bf16(U_part[jh=0] + U_part[jh=1])
//  9. gemm_bt<f32,b>  : d_out = oat @ Wout + bout
//
// Key v4 change: mix_pre computed as mfma(A=mp1,B=S) -> D2[g=4qd+c][j=r];
// lane then holds P[h][j=r] = exactly the A-frag layout for mix_post
// (dup-rule h=4qd+(e&3)) -> normalize+mix_post entirely in registers.
// ============================================================================

#define NSEQ 2048
#define DIM  1024
#define NH   16
#define DH   64
#define L2E  1.4426950408889634f
#define MH2  11.541560327111708f   /* 8 * log2(e) */

typedef unsigned short u16;
typedef unsigned int   u32;
typedef __attribute__((ext_vector_type(4))) float  f32x4;
typedef __attribute__((ext_vector_type(8))) __bf16 bf16x8;
typedef __attribute__((ext_vector_type(4))) u32    u32x4;
typedef __attribute__((ext_vector_type(2))) u32    u32x2;

__device__ __forceinline__ u16 f2bf(float f) {
  u32 u = __builtin_bit_cast(u32, f);
  u += 0x7fffu + ((u >> 16) & 1u);   // RNE
  return (u16)(u >> 16);
}

__device__ __forceinline__ f32x4 mfma16(u32x4 a, u32x4 b, f32x4 c) {
  return __builtin_amdgcn_mfma_f32_16x16x32_bf16(
      __builtin_bit_cast(bf16x8, a), __builtin_bit_cast(bf16x8, b), c, 0, 0, 0);
}

// ---------------------------------------------------------------------------
// LayerNorm: one row per block (256 thr), f32 in -> bf16 out
// ---------------------------------------------------------------------------
__launch_bounds__(256)
__global__ void ln_kernel(const float* __restrict__ x, const float* __restrict__ g,
                          const float* __restrict__ bv, u16* __restrict__ xn) {
  const int row = blockIdx.x, t = threadIdx.x;
  const float4 v = ((const float4*)(x + (size_t)row * DIM))[t];
  float s  = v.x + v.y + v.z + v.w;
  float ss = v.x * v.x + v.y * v.y + v.z * v.z + v.w * v.w;
#pragma unroll
  for (int m = 32; m; m >>= 1) { s += __shfl_xor(s, m); ss += __shfl_xor(ss, m); }
  __shared__ float red[8];
  if ((t & 63) == 0) { red[(t >> 6) * 2] = s; red[(t >> 6) * 2 + 1] = ss; }
  __syncthreads();
  s  = red[0] + red[2] + red[4] + red[6];
  ss = red[1] + red[3] + red[5] + red[7];
  const float mu  = s * (1.0f / DIM);
  const float var = ss * (1.0f / DIM) - mu * mu;
  const float rs  = rsqrtf(var + 1e-5f);
  const float4 gg = ((const float4*)g)[t];
  const float4 bb = ((const float4*)bv)[t];
  ushort4 o;
  o.x = f2bf((v.x - mu) * rs * gg.x + bb.x);
  o.y = f2bf((v.y - mu) * rs * gg.y + bb.y);
  o.z = f2bf((v.z - mu) * rs * gg.z + bb.z);
  o.w = f2bf((v.w - mu) * rs * gg.w + bb.w);
  ((ushort4*)(xn + (size_t)row * DIM))[t] = o;
}

// ---------------------------------------------------------------------------
// Weight convert+transpose: W f32 [K][N] -> WT bf16 [N][K]; 32x32 tiles
// ---------------------------------------------------------------------------
__launch_bounds__(256)
__global__ void wcvt_t(const float* __restrict__ W, u16* __restrict__ WT, int K, int N) {
  __shared__ float tile[32][33];
  const int t = threadIdx.x;
  const int k0 = blockIdx.x * 32, n0 = blockIdx.y * 32;
  {
    int ki = t >> 3, nq = t & 7;
    const float4 v = *(const float4*)(W + (size_t)(k0 + ki) * N + n0 + nq * 4);
    tile[ki][nq * 4 + 0] = v.x; tile[ki][nq * 4 + 1] = v.y;
    tile[ki][nq * 4 + 2] = v.z; tile[ki][nq * 4 + 3] = v.w;
  }
  __syncthreads();
  {
    int ni = t >> 3, kq = t & 7;
    ushort4 o;
    o.x = f2bf(tile[kq * 4 + 0][ni]); o.y = f2bf(tile[kq * 4 + 1][ni]);
    o.z = f2bf(tile[kq * 4 + 2][ni]); o.w = f2bf(tile[kq * 4 + 3][ni]);
    *(ushort4*)(WT + (size_t)(n0 + ni) * K + k0 + kq * 4) = o;
  }
}

// ---------------------------------------------------------------------------
// V transpose: VT[b][g][d][n] <- kv[b][n][1024 + g*64 + d]
// ---------------------------------------------------------------------------
__launch_bounds__(256)
__global__ void v_transpose(const u16* __restrict__ kv, u16* __restrict__ VT) {
  __shared__ u16 tile[32][72];
  const int t = threadIdx.x;
  const int n0 = blockIdx.x * 32, gh = blockIdx.y, b = blockIdx.z;
  {
    int i = t >> 3, dq = t & 7;
    u32x4 v = *(const u32x4*)(kv + ((size_t)(b * NSEQ + n0 + i)) * (2 * DIM)
                              + DIM + gh * DH + dq * 8);
    *(u32x4*)(&tile[i][dq * 8]) = v;
  }
  __syncthreads();
  {
    int d = t >> 2, nq = t & 3;
    u32x4 ov;
    ov.x = (u32)tile[nq * 8 + 0][d] | ((u32)tile[nq * 8 + 1][d] << 16);
    ov.y = (u32)tile[nq * 8 + 2][d] | ((u32)tile[nq * 8 + 3][d] << 16);
    ov.z = (u32)tile[nq * 8 + 4][d] | ((u32)tile[nq * 8 + 5][d] << 16);
    ov.w = (u32)tile[nq * 8 + 6][d] | ((u32)tile[nq * 8 + 7][d] << 16);
    *(u32x4*)(VT + ((size_t)((b * NH + gh) * DH + d)) * NSEQ + n0 + nq * 8) = ov;
  }
}

// ---------------------------------------------------------------------------
// GEMM: C[M][N] = A[M][K](bf16) * BT[N][K]^T, 128x128 tile, BK=32, 4 waves
// ---------------------------------------------------------------------------
template<int OUTF32, int BIAS>
__launch_bounds__(256)
__global__ void gemm_bt(const u16* __restrict__ A, const u16* __restrict__ BT,
                        void* __restrict__ Cp, const float* __restrict__ bias,
                        float alpha, int M, int N, int K) {
  __shared__ u16 As[128 * 32];
  __shared__ u16 Bs[128 * 32];
  const int t = threadIdx.x, lane = t & 63, r = lane & 15, q = lane >> 4;
  const int m0 = blockIdx.x * 128, n0 = blockIdx.y * 128;
  f32x4 acc[4][4] = {};
  u32x4 ra[2], rb[2];

  auto loadAB = [&](int k0) {
#pragma unroll
    for (int c = 0; c < 2; c++) {
      int u = t + 256 * c;
      int row = u >> 2, col = (u & 3) * 8;
      ra[c] = *(const u32x4*)(A  + (size_t)(m0 + row) * K + k0 + col);
      rb[c] = *(const u32x4*)(BT + (size_t)(n0 + row) * K + k0 + col);
    }
  };
  auto storeAB = [&]() {
#pragma unroll
    for (int c = 0; c < 2; c++) {
      int u = t + 256 * c;
      int row = u >> 2, col = (u & 3) * 8;
      *(u32x4*)(As + row * 32 + col) = ra[c];
      *(u32x4*)(Bs + row * 32 + col) = rb[c];
    }
  };

  loadAB(0);
  const int wr = (t >> 7) * 64;
  const int wc = ((t >> 6) & 1) * 64;
  for (int k0 = 0; k0 < K; k0 += 32) {
    storeAB();
    __syncthreads();
    if (k0 + 32 < K) loadAB(k0 + 32);
    u32x4 af[4], bf[4];
#pragma unroll
    for (int mc = 0; mc < 4; mc++)
      af[mc] = *(const u32x4*)(As + (wr + mc * 16 + r) * 32 + q * 8);
#pragma unroll
    for (int nc = 0; nc < 4; nc++)
      bf[nc] = *(const u32x4*)(Bs + (wc + nc * 16 + r) * 32 + q * 8);
#pragma unroll
    for (int mc = 0; mc < 4; mc++)
#pragma unroll
      for (int nc = 0; nc < 4; nc++)
        acc[mc][nc] = mfma16(af[mc], bf[nc], acc[mc][nc]);
    __syncthreads();
  }
#pragma unroll
  for (int mc = 0; mc < 4; mc++) {
#pragma unroll
    for (int nc = 0; nc < 4; nc++) {
#pragma unroll
      for (int e = 0; e < 4; e++) {
        int row = m0 + wr + mc * 16 + q * 4 + e;
        int col = n0 + wc + nc * 16 + r;
        float v = acc[mc][nc][e] * alpha;
        if (BIAS) v += bias[col];
        if (OUTF32) ((float*)Cp)[(size_t)row * N + col] = v;
        else        ((u16*)Cp)[(size_t)row * N + col]   = f2bf(v);
      }
    }
  }
}

// ---------------------------------------------------------------------------
// attn_a: l-only pass. Grid 512 = (8 slabs [jq x b] = XCD) x 64 i-tiles of 32.
// 8 waves; wave owns heads {2w,2w+1}. 16 steps of 32 j. K-prefetch in place.
// ---------------------------------------------------------------------------
__launch_bounds__(512, 4)
__global__ void attn_a(const u16* __restrict__ qb, const u16* __restrict__ kvb,
                       const float* __restrict__ mixpre, float* __restrict__ l_part) {
  __shared__ u16 Sb[64 * 264];   // [ch = 2*il + jc][j=16][2 gran][8 h]
  const int t = threadIdx.x, w = t >> 6, lane = t & 63, r = lane & 15, qd = lane >> 4;
  const int bid = blockIdx.x;
  const int slab = bid & 7, jq = slab >> 1, b = slab & 1;
  const int i0 = (bid >> 3) << 5;
  const f32x4 zero4 = {0.0f, 0.0f, 0.0f, 0.0f};

  // Q A-frags: A[m=i][k=d], d = kc*32 + 8qd + e
  u32x4 qf[2][2][2];
#pragma unroll
  for (int ig = 0; ig < 2; ig++)
#pragma unroll
    for (int hh = 0; hh < 2; hh++)
#pragma unroll
      for (int kc = 0; kc < 2; kc++)
        qf[ig][hh][kc] = *(const u32x4*)(qb
            + ((size_t)(b * NSEQ + i0 + ig * 16 + r)) * DIM
            + (2 * w + hh) * DH + kc * 32 + qd * 8);

  // mp1 A-frag: elem e <-> A[m=g=r][k=8qd+e], h-rule 8*(qd&1)+e, x0.5 dup
  u32x4 mpf;
  {
    u16 c[8];
#pragma unroll
    for (int e = 0; e < 8; e++)
      c[e] = f2bf(0.5f * mixpre[(8 * (qd & 1) + e) * NH + r]);
    mpf.x = (u32)c[0] | ((u32)c[1] << 16);
    mpf.y = (u32)c[2] | ((u32)c[3] << 16);
    mpf.z = (u32)c[4] | ((u32)c[5] << 16);
    mpf.w = (u32)c[6] | ((u32)c[7] << 16);
  }

  // K B-frags for step 0
  u32x4 kf[2][2][2];
  auto loadK = [&](int j0) {
#pragma unroll
    for (int hh = 0; hh < 2; hh++)
#pragma unroll
      for (int jc = 0; jc < 2; jc++)
#pragma unroll
        for (int kc = 0; kc < 2; kc++)
          kf[hh][jc][kc] = *(const u32x4*)(kvb
              + ((size_t)(b * NSEQ + j0 + jc * 16 + r)) * (2 * DIM)
              + (2 * w + hh) * DH + kc * 32 + qd * 8);
  };
  loadK(jq * 512);

  f32x4 lacc[4] = {zero4, zero4, zero4, zero4};

  for (int s = 0; s < 16; s++) {
    const int j0 = jq * 512 + s * 32;
    // ---- PH1: QK^T (A=Q m=i, B=K n=j). D[i=4qd+c][j=r]. Pack head pairs.
    const int gran = (w >> 2) ^ ((r >> 2) & 1) ^ (qd & 1);
#pragma unroll
    for (int ig = 0; ig < 2; ig++) {
#pragma unroll
      for (int jc = 0; jc < 2; jc++) {
        f32x4 s0 = mfma16(qf[ig][0][0], kf[0][jc][0], zero4);
        s0 = mfma16(qf[ig][0][1], kf[0][jc][1], s0);
        f32x4 s1 = mfma16(qf[ig][1][0], kf[1][jc][0], zero4);
        s1 = mfma16(qf[ig][1][1], kf[1][jc][1], s1);
#pragma unroll
        for (int c = 0; c < 4; c++) {
          const int ch = 2 * (ig * 16 + 4 * qd + c) + jc;
          u32 pk = (u32)f2bf(s0[c]) | ((u32)f2bf(s1[c]) << 16);
          *(u32*)(Sb + ch * 264 + r * 16 + gran * 8 + 2 * (w & 3)) = pk;
        }
      }
    }
    __syncthreads();   // bar1: S complete

    if (s + 1 < 16) loadK(j0 + 32);   // prefetch (kf dead after PH1)

    // ---- PH2: mix_pre as mfma(mp1, S) -> D2[g=4qd+c][j=r]; exp; l-accum
#pragma unroll
    for (int cc = 0; cc < 8; cc++) {
      const int ch = 8 * w + cc, slot = cc >> 1;
      const int gs = (qd & 1) ^ ((r >> 2) & 1) ^ ((ch >> 3) & 1);
      u32x4 af = *(const u32x4*)(Sb + ch * 264 + r * 16 + gs * 8);
      f32x4 d2 = mfma16(mpf, af, zero4);
      f32x4 ev;
      ev[0] = exp2f(fmaf(d2[0], L2E, -MH2));
      ev[1] = exp2f(fmaf(d2[1], L2E, -MH2));
      ev[2] = exp2f(fmaf(d2[2], L2E, -MH2));
      ev[3] = exp2f(fmaf(d2[3], L2E, -MH2));
      lacc[slot] += ev;
    }
    __syncthreads();   // bar2: Sb reads drained before next PH1
  }

  // butterfly over r-lanes (j-residues); all lanes end with the sum
#pragma unroll
  for (int slot = 0; slot < 4; slot++) {
#pragma unroll
    for (int m = 1; m <= 8; m <<= 1) {
      lacc[slot][0] += __shfl_xor(lacc[slot][0], m);
      lacc[slot][1] += __shfl_xor(lacc[slot][1], m);
      lacc[slot][2] += __shfl_xor(lacc[slot][2], m);
      lacc[slot][3] += __shfl_xor(lacc[slot][3], m);
    }
  }
  if (r == 0) {
#pragma unroll
    for (int slot = 0; slot < 4; slot++)
#pragma unroll
      for (int c = 0; c < 4; c++)
        l_part[((size_t)(slab * NH + 4 * qd + c)) * NSEQ + i0 + 4 * w + slot]
            = lacc[slot][c];
  }
}

// ---------------------------------------------------------------------------
// attn_b: recompute S2, P=e/l and mix_post in REGISTERS, P3->LDS, PV.
// Grid 512 = (4 slabs [jh x b]) x 128 i-tiles of 16. 8 waves, 32 steps.
// ---------------------------------------------------------------------------
__launch_bounds__(512, 4)
__global__ void attn_b(const u16* __restrict__ qb, const u16* __restrict__ kvb,
                       const u16* __restrict__ vtb,
                       const float* __restrict__ mixpre, const float* __restrict__ mixpost,
                       const float* __restrict__ l_part, float* __restrict__ U_part) {
  __shared__ u16 Sb[32 * 264];
  __shared__ u16 P3b[16 * 648];   // [g'][i16][32 j + 8 pad]
  const int t = threadIdx.x, w = t >> 6, lane = t & 63, r = lane & 15, qd = lane >> 4;
  const int bid = blockIdx.x;
  const int slab4 = bid & 3, jh = slab4 >> 1, b = slab4 & 1;
  const int i0 = (bid >> 2) << 4;
  const f32x4 zero4 = {0.0f, 0.0f, 0.0f, 0.0f};

  u32x4 qf[2][2];
#pragma unroll
  for (int hh = 0; hh < 2; hh++)
#pragma unroll
    for (int kc = 0; kc < 2; kc++)
      qf[hh][kc] = *(const u32x4*)(qb + ((size_t)(b * NSEQ + i0 + r)) * DIM
                                   + (2 * w + hh) * DH + kc * 32 + qd * 8);

  // mp1 A-frag (h-rule 8*(qd&1)+e) and mp2 B-frag (h-rule 4qd+(e&3)), x0.5
  u32x4 mpf, mp2f;
  {
    u16 c[8];
#pragma unroll
    for (int e = 0; e < 8; e++)
      c[e] = f2bf(0.5f * mixpre[(8 * (qd & 1) + e) * NH + r]);
    mpf.x = (u32)c[0] | ((u32)c[1] << 16);
    mpf.y = (u32)c[2] | ((u32)c[3] << 16);
    mpf.z = (u32)c[4] | ((u32)c[5] << 16);
    mpf.w = (u32)c[6] | ((u32)c[7] << 16);
#pragma unroll
    for (int e = 0; e < 8; e++)
      c[e] = f2bf(0.5f * mixpost[(4 * qd + (e & 3)) * NH + r]);
    mp2f.x = (u32)c[0] | ((u32)c[1] << 16);
    mp2f.y = (u32)c[2] | ((u32)c[3] << 16);
    mp2f.z = (u32)c[4] | ((u32)c[5] << 16);
    mp2f.w = (u32)c[6] | ((u32)c[7] << 16);
  }

  // rl[ii][c] = 1 / sum_jq l_part[jq,b, g=4qd+c, i0+2w+ii]
  float rl[2][4];
#pragma unroll
  for (int ii = 0; ii < 2; ii++)
#pragma unroll
    for (int c = 0; c < 4; c++) {
      float lv = 0.0f;
#pragma unroll
      for (int jqq = 0; jqq < 4; jqq++)
        lv += l_part[((size_t)((jqq * 2 + b) * NH + 4 * qd + c)) * NSEQ + i0 + 2 * w + ii];
      rl[ii][c] = 1.0f / lv;
    }

  u32x4 kf[2][2][2];
  auto loadK = [&](int j0) {
#pragma unroll
    for (int hh = 0; hh < 2; hh++)
#pragma unroll
      for (int jc = 0; jc < 2; jc++)
#pragma unroll
        for (int kc = 0; kc < 2; kc++)
          kf[hh][jc][kc] = *(const u32x4*)(kvb
              + ((size_t)(b * NSEQ + j0 + jc * 16 + r)) * (2 * DIM)
              + (2 * w + hh) * DH + kc * 32 + qd * 8);
  };
  loadK(jh * 1024);

  f32x4 U[2][4];
#pragma unroll
  for (int hh = 0; hh < 2; hh++)
#pragma unroll
    for (int dc = 0; dc < 4; dc++) U[hh][dc] = zero4;

  for (int s = 0; s < 32; s++) {
    const int j0 = jh * 1024 + s * 32;
    // ---- PH1: QK^T, pack head pairs into Sb
    const int gran = (w >> 2) ^ ((r >> 2) & 1) ^ (qd & 1);
#pragma unroll
    for (int jc = 0; jc < 2; jc++) {
      f32x4 s0 = mfma16(qf[0][0], kf[0][jc][0], zero4);
      s0 = mfma16(qf[0][1], kf[0][jc][1], s0);
      f32x4 s1 = mfma16(qf[1][0], kf[1][jc][0], zero4);
      s1 = mfma16(qf[1][1], kf[1][jc][1], s1);
#pragma unroll
      for (int c = 0; c < 4; c++) {
        const int ch = 2 * (4 * qd + c) + jc;
        u32 pk = (u32)f2bf(s0[c]) | ((u32)f2bf(s1[c]) << 16);
        *(u32*)(Sb + ch * 264 + r * 16 + gran * 8 + 2 * (w & 3)) = pk;
      }
    }
    __syncthreads();   // bar1

    if (s + 1 < 32) loadK(j0 + 32);   // prefetch

    // ---- PH2: mix_pre -> exp -> normalize -> mix_post (ALL registers) -> P3
#pragma unroll
    for (int cc = 0; cc < 4; cc++) {
      const int ch = 4 * w + cc, ii = cc >> 1, jc = cc & 1;
      const int gs = (qd & 1) ^ ((r >> 2) & 1) ^ ((ch >> 3) & 1);
      u32x4 af = *(const u32x4*)(Sb + ch * 264 + r * 16 + gs * 8);
      f32x4 d2 = mfma16(mpf, af, zero4);   // D2[g=4qd+c][j=r]
      float pv0 = exp2f(fmaf(d2[0], L2E, -MH2)) * rl[ii][0];
      float pv1 = exp2f(fmaf(d2[1], L2E, -MH2)) * rl[ii][1];
      float pv2 = exp2f(fmaf(d2[2], L2E, -MH2)) * rl[ii][2];
      float pv3 = exp2f(fmaf(d2[3], L2E, -MH2)) * rl[ii][3];
      // dup-pack: A-frag [m=j=r][k], h-rule 4qd+(e&3)
      u32x4 pa;
      pa.x = (u32)f2bf(pv0) | ((u32)f2bf(pv1) << 16);
      pa.y = (u32)f2bf(pv2) | ((u32)f2bf(pv3) << 16);
      pa.z = pa.x; pa.w = pa.y;
      f32x4 d3 = mfma16(pa, mp2f, zero4);  // D3[j=4qd+c][g'=r]
      u32x2 pk;
      pk.x = (u32)f2bf(d3[0]) | ((u32)f2bf(d3[1]) << 16);
      pk.y = (u32)f2bf(d3[2]) | ((u32)f2bf(d3[3]) << 16);
      *(u32x2*)(P3b + r * 648 + (2 * w + ii) * 40 + jc * 16 + 4 * qd) = pk;
    }
    __syncthreads();   // bar2: P3 complete

    // ---- PH4: PV, heads g' = {2w, 2w+1}
#pragma unroll
    for (int hh = 0; hh < 2; hh++) {
      const int g = 2 * w + hh;
      u32x4 paf = *(const u32x4*)(P3b + g * 648 + r * 40 + 8 * qd);
#pragma unroll
      for (int dc = 0; dc < 4; dc++) {
        u32x4 vf = *(const u32x4*)(vtb
            + ((size_t)((b * NH + g) * DH + dc * 16 + r)) * NSEQ + j0 + 8 * qd);
        U[hh][dc] = mfma16(paf, vf, U[hh][dc]);
      }
    }
    // PH4 P3 reads drain at next bar1 before PH2 overwrites
  }

#pragma unroll
  for (int hh = 0; hh < 2; hh++)
#pragma unroll
    for (int dc = 0; dc < 4; dc++)
#pragma unroll
      for (int e = 0; e < 4; e++)
        U_part[((size_t)((jh * 2 + b) * NSEQ + i0 + 4 * qd + e)) * DIM
               + (2 * w + hh) * DH + dc * 16 + r] = U[hh][dc][e];
}

// ---------------------------------------------------------------------------
// combine: oat = bf16(U_part[jh=0] + U_part[jh=1])
// ---------------------------------------------------------------------------
__launch_bounds__(256)
__global__ void combine(const float* __restrict__ U, u16* __restrict__ oat) {
  const size_t x = ((size_t)blockIdx.x * 256 + threadIdx.x) * 4;
  float4 a = *(const float4*)(U + x);
  float4 c = *(const float4*)(U + x + (size_t)4 * 1024 * 1024);
  u32x2 pk;
  pk.x = (u32)f2bf(a.x + c.x) | ((u32)f2bf(a.y + c.y) << 16);
  pk.y = (u32)f2bf(a.z + c.z) | ((u32)f2bf(a.w + c.w) << 16);
  *(u32x2*)(oat + x) = pk;
}

// ---------------------------------------------------------------------------
extern "C" void kernel_launch(void* const* d_in, const int* in_sizes, int n_in,
                              void* d_out, int out_size, void* d_ws, size_t ws_size,
                              hipStream_t stream) {
  (void)in_sizes; (void)n_in; (void)out_size; (void)ws_size;
  const float* x       = (const float*)d_in[0];
  const float* ln_g    = (const float*)d_in[1];
  const float* ln_b    = (const float*)d_in[2];
  const float* Wq      = (const float*)d_in[3];
  const float* Wkv     = (const float*)d_in[4];
  const float* mixpre  = (const float*)d_in[5];
  const float* mixpost = (const float*)d_in[6];
  const float* Wout    = (const float*)d_in[7];
  const float* bout    = (const float*)d_in[8];
  float* out = (float*)d_out;

  char* p = (char*)d_ws;
  auto alloc = [&](size_t bytes) {
    char* rp = p; p += (bytes + 255) & ~(size_t)255; return rp;
  };
  u16*   xn    = (u16*)alloc((size_t)4096 * 1024 * 2);
  u16*   WqT   = (u16*)alloc((size_t)1024 * 1024 * 2);
  u16*   WkvT  = (u16*)alloc((size_t)2048 * 1024 * 2);
  u16*   WoutT = (u16*)alloc((size_t)1024 * 1024 * 2);
  u16*   qb    = (u16*)alloc((size_t)4096 * 1024 * 2);
  u16*   kvb   = (u16*)alloc((size_t)4096 * 2048 * 2);
  u16*   VTb   = (u16*)alloc((size_t)2 * NH * DH * NSEQ * 2);
  float* lpart = (float*)alloc((size_t)8 * NH * NSEQ * 4);
  float* Upart = (float*)alloc((size_t)4 * NSEQ * DIM * 4);   // 32 MB
  u16*   oat   = (u16*)alloc((size_t)4096 * 1024 * 2);

  ln_kernel<<<4096, 256, 0, stream>>>(x, ln_g, ln_b, xn);
  wcvt_t<<<dim3(32, 32), 256, 0, stream>>>(Wq,   WqT,   1024, 1024);
  wcvt_t<<<dim3(32, 64), 256, 0, stream>>>(Wkv,  WkvT,  1024, 2048);
  wcvt_t<<<dim3(32, 32), 256, 0, stream>>>(Wout, WoutT, 1024, 1024);
  gemm_bt<0, 0><<<dim3(32, 8),  256, 0, stream>>>(xn, WqT,  qb,  nullptr, 0.125f, 4096, 1024, 1024);
  gemm_bt<0, 0><<<dim3(32, 16), 256, 0, stream>>>(xn, WkvT, kvb, nullptr, 1.0f,   4096, 2048, 1024);
  v_transpose<<<dim3(64, 16, 2), 256, 0, stream>>>(kvb, VTb);
  attn_a<<<512, 512, 0, stream>>>(qb, kvb, mixpre, lpart);
  attn_b<<<512, 512, 0, stream>>>(qb, kvb, VTb, mixpre, mixpost, lpart, Upart);
  combine<<<4096, 256, 0, stream>>>(Upart, oat);
  gemm_bt<1, 1><<<dim3(32, 8), 256, 0, stream>>>(oat, WoutT, out, bout, 1.0f, 4096, 1024, 1024);
}